// Round 1
// baseline (135.107 us; speedup 1.0000x reference)
//
#include <hip/hip_runtime.h>
#include <math.h>

// Problem constants (from setup_inputs): B=2, T=15, H=W=192, C=P=16
#define HW_TOT 36864      // 192*192
#define T_LEN  15
#define NSEQ   73728      // 2*36864  (= 1152 * 64)

// ws layout (floats):
//    0: P1re[16]   16: P1im[16]   32: P2re[16]   48: P2im[16]
//   64: P3re[16]   80: P3im[16]   96: Lre[16]   112: Lim[16]
//  128: Saa, 2*Sad, Sdd, pad
//  132: F1[16] 148: F2[16] 164: F3[16] 180: D[16]
//  196: Cmre[c*16+p] (256)  452: Cmim[c*16+p] (256)
//  708: Wenc[j*16+c] (512) 1220: Wdec[c*16+k] (256)
// 1476: ffg[16] 1492: ffb[16] 1508: outg[16] 1524: outb[16]
// 1540: Wout[c*16+k] (256) 1796: bout[16]   -> total 1812 floats (7248 B)

__device__ __forceinline__ float gelu_exact(float x){
  // 0.5*x*(1+erf(x/sqrt(2))); erf via Abramowitz-Stegun 7.1.26 (|err|<1.5e-7)
  float ax = fabsf(x) * 0.7071067811865476f;
  float t  = 1.0f / (1.0f + 0.3275911f * ax);
  float poly = t*(0.254829592f + t*(-0.284496736f + t*(1.421413741f +
               t*(-1.453152027f + t*1.061405429f))));
  float er = 1.0f - poly * __expf(-ax*ax);
  er = copysignf(er, x);
  return 0.5f * x * (1.0f + er);
}

__global__ void __launch_bounds__(64) ssm_setup(
    const float* __restrict__ w_in, const float* __restrict__ b_in,
    const float* __restrict__ ag,   const float* __restrict__ ab,
    const float* __restrict__ Lre,  const float* __restrict__ Lim,
    const float* __restrict__ Bre,  const float* __restrict__ Bim,
    const float* __restrict__ Cre,  const float* __restrict__ Cim,
    const float* __restrict__ Dv,   const float* __restrict__ ls,
    const float* __restrict__ ffg,  const float* __restrict__ ffb,
    const float* __restrict__ Wenc, const float* __restrict__ Wdec,
    const float* __restrict__ og,   const float* __restrict__ ob,
    const float* __restrict__ Wout, const float* __restrict__ bout,
    float* __restrict__ ws)
{
  const int tid = threadIdx.x;   // 64 threads, one wave

  // redundant per-thread scalar stats over C=16 (cheap)
  float mw = 0.f, mb = 0.f;
  for (int c = 0; c < 16; ++c){ mw += w_in[c]; mb += b_in[c]; }
  mw *= 0.0625f; mb *= 0.0625f;
  float Saa = 0.f, Sad = 0.f, Sdd = 0.f;
  for (int c = 0; c < 16; ++c){
    float a = w_in[c]-mw, d = b_in[c]-mb;
    Saa += a*a; Sad += a*d; Sdd += d*d;
  }
  Saa *= 0.0625f; Sad *= 0.0625f; Sdd *= 0.0625f;
  if (tid == 0){ ws[128]=Saa; ws[129]=2.f*Sad; ws[130]=Sdd; ws[131]=0.f; }

  if (tid < 16){
    int c = tid;
    float a = w_in[c]-mw, d = b_in[c]-mb, g = ag[c];
    ws[132+c] = a*g;      // F1
    ws[148+c] = d*g;      // F2
    ws[164+c] = ab[c];    // F3
    ws[180+c] = Dv[c];
  }

  if (tid < 16){
    int p = tid;
    float step = expf(ls[p]);          // STEP_SCALE = 1
    float lr = Lre[p], li = Lim[p];
    float er = expf(lr*step);
    float th = li*step;
    float Lbr = er*cosf(th), Lbi = er*sinf(th);   // Lam_bar
    ws[96+p] = Lbr; ws[112+p] = Lbi;
    // Bfac = (Lam_bar - 1)/Lam   (complex)
    float inv = 1.f/(lr*lr + li*li);
    float gr = Lbr - 1.f, gi = Lbi;
    float fr = (gr*lr + gi*li)*inv;
    float fi = (gi*lr - gr*li)*inv;
    float P1r=0,P1i=0,P2r=0,P2i=0,P3r=0,P3i=0;
    for (int c = 0; c < 16; ++c){
      float br = Bre[p*16+c], bi = Bim[p*16+c];
      float Bbr = fr*br - fi*bi, Bbi = fr*bi + fi*br;   // B_bar[p][c]
      float a = w_in[c]-mw, d = b_in[c]-mb, g = ag[c];
      float f1 = a*g, f2 = d*g, f3 = ab[c];
      P1r += f1*Bbr; P1i += f1*Bbi;
      P2r += f2*Bbr; P2i += f2*Bbi;
      P3r += f3*Bbr; P3i += f3*Bbi;
    }
    ws[ 0+p]=P1r; ws[16+p]=P1i; ws[32+p]=P2r;
    ws[48+p]=P2i; ws[64+p]=P3r; ws[80+p]=P3i;
  }

  // Cm with bandlimit mask (mask over p)
  for (int k = tid; k < 256; k += 64){
    int p = k & 15;
    float step = expf(ls[p]);
    float freq = step * fabsf(Lim[p]) * 0.15915494309189535f;  // /(2*pi)
    float m = (freq < 0.25f) ? 1.f : 0.f;                      // BANDLIMIT*0.5
    ws[196+k] = Cre[k]*m;
    ws[452+k] = Cim[k]*m;
  }
  for (int k = tid; k < 512; k += 64) ws[ 708+k] = Wenc[k];
  for (int k = tid; k < 256; k += 64) ws[1220+k] = Wdec[k];
  for (int k = tid; k < 256; k += 64) ws[1540+k] = Wout[k];
  if (tid < 16){
    ws[1476+tid] = ffg[tid];
    ws[1492+tid] = ffb[tid];
    ws[1508+tid] = og[tid];
    ws[1524+tid] = ob[tid];
    ws[1796+tid] = bout[tid];
  }
}

__global__ void __launch_bounds__(64) ssm_main(
    const float* __restrict__ x, const float* __restrict__ ws,
    float* __restrict__ out)
{
  const int n   = blockIdx.x * 64 + threadIdx.x;     // sequence id, < NSEQ
  const int b   = (n >= HW_TOT) ? 1 : 0;
  const int rem = n - b * HW_TOT;

  // prefetch all T inputs (coalesced: consecutive lanes -> consecutive rem)
  const float* xp = x + (size_t)b * (T_LEN * HW_TOT) + rem;
  float xv[T_LEN];
#pragma unroll
  for (int t = 0; t < T_LEN; ++t) xv[t] = xp[(size_t)t * HW_TOT];

  const float Saa = ws[128], Sad2 = ws[129], Sdd = ws[130];
  float P1r[16],P1i[16],P2r[16],P2i[16],P3r[16],P3i[16],Lr[16],Li[16];
#pragma unroll
  for (int p = 0; p < 16; ++p){
    P1r[p]=ws[p];    P1i[p]=ws[16+p];
    P2r[p]=ws[32+p]; P2i[p]=ws[48+p];
    P3r[p]=ws[64+p]; P3i[p]=ws[80+p];
    Lr[p] =ws[96+p]; Li[p] =ws[112+p];
  }

  float sre[16], sim_[16];
#pragma unroll
  for (int p = 0; p < 16; ++p){ sre[p]=0.f; sim_[p]=0.f; }

  float rstdL = 0.f, s1L = 0.f;
#pragma unroll
  for (int t = 0; t < T_LEN; ++t){
    const float xvt  = xv[t];
    const float var  = fmaf(xvt, fmaf(xvt, Saa, Sad2), Sdd);  // mean((u-mu)^2)
    const float rstd = rsqrtf(var + 1e-5f);
    const float s1   = rstd * xvt;
#pragma unroll
    for (int p = 0; p < 16; ++p){
      // Bu_p = fx . B_bar[p]  collapsed to affine form
      const float br = fmaf(s1, P1r[p], fmaf(rstd, P2r[p], P3r[p]));
      const float bi = fmaf(s1, P1i[p], fmaf(rstd, P2i[p], P3i[p]));
      // s = Lam_bar * s + Bu
      const float nr = fmaf(Lr[p], sre[p], fmaf(-Li[p], sim_[p], br));
      const float ni = fmaf(Lr[p], sim_[p], fmaf( Li[p], sre[p], bi));
      sre[p] = nr; sim_[p] = ni;
    }
    rstdL = rstd; s1L = s1;
  }

  // ---- tail: only needed at t = T-1 ----
  float fx[16];
#pragma unroll
  for (int c = 0; c < 16; ++c)
    fx[c] = fmaf(s1L, ws[132+c], fmaf(rstdL, ws[148+c], ws[164+c]));

  // y = Re(s . Cm[c,:]) + fx*D ;  z = gelu(y) + fx
  float z[16];
#pragma unroll
  for (int c = 0; c < 16; ++c){
    float acc = fx[c] * ws[180+c];
#pragma unroll
    for (int p = 0; p < 16; ++p){
      acc = fmaf(sre[p],   ws[196 + c*16 + p], acc);
      acc = fmaf(-sim_[p], ws[452 + c*16 + p], acc);
    }
    z[c] = gelu_exact(acc) + fx[c];
  }

  // LN(z) -> fx2
  float mu = 0.f;
#pragma unroll
  for (int c = 0; c < 16; ++c) mu += z[c];
  mu *= 0.0625f;
  float vr = 0.f;
#pragma unroll
  for (int c = 0; c < 16; ++c){ float d = z[c]-mu; vr = fmaf(d,d,vr); }
  vr *= 0.0625f;
  float rs = rsqrtf(vr + 1e-5f);
  float fx2[16];
#pragma unroll
  for (int c = 0; c < 16; ++c)
    fx2[c] = fmaf((z[c]-mu)*rs, ws[1476+c], ws[1492+c]);

  // enc = fx2 @ Wenc^T ; h = a * gelu(g)
  float hg[16];
#pragma unroll
  for (int c = 0; c < 16; ++c){
    float a = 0.f, g = 0.f;
#pragma unroll
    for (int k = 0; k < 16; ++k){
      a = fmaf(fx2[k], ws[708 + c*16 + k], a);
      g = fmaf(fx2[k], ws[708 + (16+c)*16 + k], g);
    }
    hg[c] = a * gelu_exact(g);
  }

  // z2 = hg @ Wdec^T + fx2
  float z2[16];
#pragma unroll
  for (int c = 0; c < 16; ++c){
    float acc = fx2[c];
#pragma unroll
    for (int k = 0; k < 16; ++k) acc = fmaf(hg[k], ws[1220 + c*16 + k], acc);
    z2[c] = acc;
  }

  // final LN + out head
  float mu3 = 0.f;
#pragma unroll
  for (int c = 0; c < 16; ++c) mu3 += z2[c];
  mu3 *= 0.0625f;
  float v3 = 0.f;
#pragma unroll
  for (int c = 0; c < 16; ++c){ float d = z2[c]-mu3; v3 = fmaf(d,d,v3); }
  v3 *= 0.0625f;
  float rs3 = rsqrtf(v3 + 1e-5f);
  float q[16];
#pragma unroll
  for (int c = 0; c < 16; ++c)
    q[c] = fmaf((z2[c]-mu3)*rs3, ws[1508+c], ws[1524+c]);

  float* op = out + (size_t)b * (16*HW_TOT) + rem;
#pragma unroll
  for (int c = 0; c < 16; ++c){
    float acc = ws[1796+c];
#pragma unroll
    for (int k = 0; k < 16; ++k) acc = fmaf(q[k], ws[1540 + c*16 + k], acc);
    op[(size_t)c * HW_TOT] = acc;   // (b, c, h, w), coalesced per c
  }
}

extern "C" void kernel_launch(void* const* d_in, const int* in_sizes, int n_in,
                              void* d_out, int out_size, void* d_ws, size_t ws_size,
                              hipStream_t stream)
{
  const float* x    = (const float*)d_in[0];
  const float* w_in = (const float*)d_in[1];
  const float* b_in = (const float*)d_in[2];
  const float* ag   = (const float*)d_in[3];
  const float* ab   = (const float*)d_in[4];
  const float* Lre  = (const float*)d_in[5];
  const float* Lim  = (const float*)d_in[6];
  const float* Bre  = (const float*)d_in[7];
  const float* Bim  = (const float*)d_in[8];
  const float* Cre  = (const float*)d_in[9];
  const float* Cim  = (const float*)d_in[10];
  const float* Dv   = (const float*)d_in[11];
  const float* ls   = (const float*)d_in[12];
  const float* ffg  = (const float*)d_in[13];
  const float* ffb  = (const float*)d_in[14];
  const float* Wenc = (const float*)d_in[15];
  const float* Wdec = (const float*)d_in[16];
  const float* og   = (const float*)d_in[17];
  const float* ob   = (const float*)d_in[18];
  const float* Wout = (const float*)d_in[19];
  const float* bout = (const float*)d_in[20];
  float* ws  = (float*)d_ws;
  float* out = (float*)d_out;

  ssm_setup<<<1, 64, 0, stream>>>(w_in, b_in, ag, ab, Lre, Lim, Bre, Bim,
                                  Cre, Cim, Dv, ls, ffg, ffb, Wenc, Wdec,
                                  og, ob, Wout, bout, ws);
  ssm_main<<<NSEQ/64, 64, 0, stream>>>(x, ws, out);
}

// Round 3
// 122.414 us; speedup vs baseline: 1.1037x; 1.1037x over previous
//
#include <hip/hip_runtime.h>
#include <math.h>

// Problem constants: B=2, T=15, H=W=192, C=P=16
#define HW_TOT 36864      // 192*192
#define T_LEN  15
#define NSEQ   73728      // 2*36864 = 1152*64
#define WS_N   1812

// ws layout (floats):
//    0: Lr[16]    16: Li[16]          (Lam_bar)
//   32: P1r[16]   48: P1i[16]         (B_bar . F1, coeff of s1)
//   64: P2r[16]   80: P2i[16]         (B_bar . F2, coeff of rstd)
//   96: Qr[16]   112: Qi[16]          (P3 * sum_j Lam_bar^j)
//  128: Saa, 2*Sad, Sdd, pad
//  132: F1[16] 148: F2[16] 164: F3[16] 180: D[16]
//  196: Cmr[c*16+p] 256   452: Cmi[c*16+p] 256
//  708: Wenc[j*16+k] 512
// 1220: Wdec[c*16+k] 256
// 1476: Wout[c*16+k] 256
// 1732: ffg 1748: ffb 1764: og 1780: ob 1796: bout  -> 1812 floats

__device__ __forceinline__ float gelu_exact(float x){
  float ax = fabsf(x) * 0.7071067811865476f;
  float t  = 1.0f / (1.0f + 0.3275911f * ax);
  float poly = t*(0.254829592f + t*(-0.284496736f + t*(1.421413741f +
               t*(-1.453152027f + t*1.061405429f))));
  float er = 1.0f - poly * __expf(-ax*ax);
  er = copysignf(er, x);
  return 0.5f * x * (1.0f + er);
}

__global__ void __launch_bounds__(64) ssm_setup(
    const float* __restrict__ w_in, const float* __restrict__ b_in,
    const float* __restrict__ ag,   const float* __restrict__ ab,
    const float* __restrict__ Lre,  const float* __restrict__ Lim,
    const float* __restrict__ Bre,  const float* __restrict__ Bim,
    const float* __restrict__ Cre,  const float* __restrict__ Cim,
    const float* __restrict__ Dv,   const float* __restrict__ ls,
    const float* __restrict__ ffg,  const float* __restrict__ ffb,
    const float* __restrict__ Wenc, const float* __restrict__ Wdec,
    const float* __restrict__ og,   const float* __restrict__ ob,
    const float* __restrict__ Wout, const float* __restrict__ bout,
    float* __restrict__ ws)
{
  const int tid = threadIdx.x;

  float mw = 0.f, mb = 0.f;
  for (int c = 0; c < 16; ++c){ mw += w_in[c]; mb += b_in[c]; }
  mw *= 0.0625f; mb *= 0.0625f;
  float Saa = 0.f, Sad = 0.f, Sdd = 0.f;
  for (int c = 0; c < 16; ++c){
    float a = w_in[c]-mw, d = b_in[c]-mb;
    Saa += a*a; Sad += a*d; Sdd += d*d;
  }
  Saa *= 0.0625f; Sad *= 0.0625f; Sdd *= 0.0625f;
  if (tid == 0){ ws[128]=Saa; ws[129]=2.f*Sad; ws[130]=Sdd; ws[131]=0.f; }

  if (tid < 16){
    int c = tid;
    float a = w_in[c]-mw, d = b_in[c]-mb, g = ag[c];
    ws[132+c] = a*g;      // F1
    ws[148+c] = d*g;      // F2
    ws[164+c] = ab[c];    // F3
    ws[180+c] = Dv[c];
  }

  if (tid < 16){
    int p = tid;
    float step = expf(ls[p]);
    float lr = Lre[p], li = Lim[p];
    float er = expf(lr*step);
    float th = li*step;
    float Lbr = er*cosf(th), Lbi = er*sinf(th);   // Lam_bar
    ws[0+p] = Lbr; ws[16+p] = Lbi;
    float inv = 1.f/(lr*lr + li*li);
    float gr = Lbr - 1.f, gi = Lbi;
    float fr = (gr*lr + gi*li)*inv;
    float fi = (gi*lr - gr*li)*inv;
    float P1r=0,P1i=0,P2r=0,P2i=0,P3r=0,P3i=0;
    for (int c = 0; c < 16; ++c){
      float br = Bre[p*16+c], bi = Bim[p*16+c];
      float Bbr = fr*br - fi*bi, Bbi = fr*bi + fi*br;   // B_bar[p][c]
      float a = w_in[c]-mw, d = b_in[c]-mb, g = ag[c];
      float f1 = a*g, f2 = d*g, f3 = ab[c];
      P1r += f1*Bbr; P1i += f1*Bbi;
      P2r += f2*Bbr; P2i += f2*Bbi;
      P3r += f3*Bbr; P3i += f3*Bbi;
    }
    ws[32+p]=P1r; ws[48+p]=P1i;
    ws[64+p]=P2r; ws[80+p]=P2i;
    // K = sum_{j=0..14} Lam_bar^j ; Q = P3 * K
    float kr=1.f, ki=0.f, cr_=1.f, ci_=0.f;
    for (int j = 1; j < T_LEN; ++j){
      float nr = cr_*Lbr - ci_*Lbi;
      float ni = cr_*Lbi + ci_*Lbr;
      cr_ = nr; ci_ = ni;
      kr += cr_; ki += ci_;
    }
    ws[ 96+p] = P3r*kr - P3i*ki;
    ws[112+p] = P3r*ki + P3i*kr;
  }

  for (int k = tid; k < 256; k += 64){
    int p = k & 15;
    float step = expf(ls[p]);
    float freq = step * fabsf(Lim[p]) * 0.15915494309189535f;
    float m = (freq < 0.25f) ? 1.f : 0.f;
    ws[196+k] = Cre[k]*m;
    ws[452+k] = Cim[k]*m;
  }
  for (int k = tid; k < 512; k += 64) ws[ 708+k] = Wenc[k];
  for (int k = tid; k < 256; k += 64) ws[1220+k] = Wdec[k];
  for (int k = tid; k < 256; k += 64) ws[1476+k] = Wout[k];
  if (tid < 16){
    ws[1732+tid] = ffg[tid];
    ws[1748+tid] = ffb[tid];
    ws[1764+tid] = og[tid];
    ws[1780+tid] = ob[tid];
    ws[1796+tid] = bout[tid];
  }
}

__global__ void __launch_bounds__(64) ssm_main(
    const float* __restrict__ x, const float* __restrict__ ws,
    float* __restrict__ out)
{
  __shared__ float sm[WS_N];
  // stage params global -> LDS (coalesced); one wave per block.
  for (int k = threadIdx.x; k < WS_N; k += 64) sm[k] = ws[k];

  const int n   = blockIdx.x * 64 + threadIdx.x;
  const int b   = (n >= HW_TOT) ? 1 : 0;
  const int rem = n - b * HW_TOT;

  // prefetch x while staging is in flight (coalesced per t)
  const float* xp = x + (size_t)b * (T_LEN * HW_TOT) + rem;
  float xv[T_LEN];
#pragma unroll
  for (int t = 0; t < T_LEN; ++t) xv[t] = xp[(size_t)t * HW_TOT];

  __syncthreads();

  float Lr[16], Li[16];
#pragma unroll
  for (int p = 0; p < 16; ++p){ Lr[p] = sm[p]; Li[p] = sm[16+p]; }
  const float Saa = sm[128], Sad2 = sm[129], Sdd = sm[130];

  // Horner accumulators: s_{T-1} = P1*A1 + P2*A2 + Q (complex per p)
  float A1r[16], A1i[16], A2r[16], A2i[16];
#pragma unroll
  for (int p = 0; p < 16; ++p){ A1r[p]=0.f; A1i[p]=0.f; A2r[p]=0.f; A2i[p]=0.f; }

  float rstdL = 0.f, s1L = 0.f;
#pragma unroll
  for (int t = 0; t < T_LEN; ++t){
    const float xvt  = xv[t];
    const float var  = fmaf(xvt, fmaf(xvt, Saa, Sad2), Sdd);
    const float rstd = rsqrtf(var + 1e-5f);
    const float s1   = rstd * xvt;
#pragma unroll
    for (int p = 0; p < 16; ++p){
      float n1r = fmaf(Lr[p], A1r[p], fmaf(-Li[p], A1i[p], s1));
      float n1i = fmaf(Lr[p], A1i[p], Li[p]*A1r[p]);
      A1r[p] = n1r; A1i[p] = n1i;
      float n2r = fmaf(Lr[p], A2r[p], fmaf(-Li[p], A2i[p], rstd));
      float n2i = fmaf(Lr[p], A2i[p], Li[p]*A2r[p]);
      A2r[p] = n2r; A2i[p] = n2i;
    }
    rstdL = rstd; s1L = s1;
  }

  // reconstruct final state s (complex per p)
  float sre[16], sim_[16];
#pragma unroll
  for (int p = 0; p < 16; ++p){
    float p1r = sm[32+p], p1i = sm[48+p];
    float p2r = sm[64+p], p2i = sm[80+p];
    float r = sm[96+p], im = sm[112+p];
    r  = fmaf(p1r, A1r[p], fmaf(-p1i, A1i[p], r));
    r  = fmaf(p2r, A2r[p], fmaf(-p2i, A2i[p], r));
    im = fmaf(p1r, A1i[p], fmaf( p1i, A1r[p], im));
    im = fmaf(p2r, A2i[p], fmaf( p2i, A2r[p], im));
    sre[p] = r; sim_[p] = im;
  }

  // fx at t = T-1
  float fx[16];
#pragma unroll
  for (int c = 0; c < 16; ++c)
    fx[c] = fmaf(s1L, sm[132+c], fmaf(rstdL, sm[148+c], sm[164+c]));

  // y = Re(s . Cm[c,:]) + fx*D ; z = gelu(y) + fx
  float z[16];
#pragma unroll
  for (int c = 0; c < 16; ++c){
    float acc = fx[c] * sm[180+c];
#pragma unroll
    for (int p = 0; p < 16; ++p){
      acc = fmaf(sre[p],   sm[196 + c*16 + p], acc);
      acc = fmaf(-sim_[p], sm[452 + c*16 + p], acc);
    }
    z[c] = gelu_exact(acc) + fx[c];
  }

  // LN(z) -> fx2
  float mu = 0.f;
#pragma unroll
  for (int c = 0; c < 16; ++c) mu += z[c];
  mu *= 0.0625f;
  float vr = 0.f;
#pragma unroll
  for (int c = 0; c < 16; ++c){ float d = z[c]-mu; vr = fmaf(d,d,vr); }
  vr *= 0.0625f;
  float rs = rsqrtf(vr + 1e-5f);
  float fx2[16];
#pragma unroll
  for (int c = 0; c < 16; ++c)
    fx2[c] = fmaf((z[c]-mu)*rs, sm[1732+c], sm[1748+c]);

  // enc = fx2 @ Wenc^T ; h = a * gelu(g)
  float hg[16];
#pragma unroll
  for (int c = 0; c < 16; ++c){
    float a = 0.f, g = 0.f;
#pragma unroll
    for (int k = 0; k < 16; ++k){
      a = fmaf(fx2[k], sm[708 + c*16 + k], a);
      g = fmaf(fx2[k], sm[708 + (16+c)*16 + k], g);
    }
    hg[c] = a * gelu_exact(g);
  }

  // z2 = hg @ Wdec^T + fx2
  float z2[16];
#pragma unroll
  for (int c = 0; c < 16; ++c){
    float acc = fx2[c];
#pragma unroll
    for (int k = 0; k < 16; ++k) acc = fmaf(hg[k], sm[1220 + c*16 + k], acc);
    z2[c] = acc;
  }

  // final LN + out head
  float mu3 = 0.f;
#pragma unroll
  for (int c = 0; c < 16; ++c) mu3 += z2[c];
  mu3 *= 0.0625f;
  float v3 = 0.f;
#pragma unroll
  for (int c = 0; c < 16; ++c){ float d = z2[c]-mu3; v3 = fmaf(d,d,v3); }
  v3 *= 0.0625f;
  float rs3 = rsqrtf(v3 + 1e-5f);
  float qv[16];
#pragma unroll
  for (int c = 0; c < 16; ++c)
    qv[c] = fmaf((z2[c]-mu3)*rs3, sm[1764+c], sm[1780+c]);

  float* op = out + (size_t)b * (16*HW_TOT) + rem;
#pragma unroll
  for (int c = 0; c < 16; ++c){
    float acc = sm[1796+c];
#pragma unroll
    for (int k = 0; k < 16; ++k) acc = fmaf(qv[k], sm[1476 + c*16 + k], acc);
    op[(size_t)c * HW_TOT] = acc;
  }
}

extern "C" void kernel_launch(void* const* d_in, const int* in_sizes, int n_in,
                              void* d_out, int out_size, void* d_ws, size_t ws_size,
                              hipStream_t stream)
{
  const float* x    = (const float*)d_in[0];
  const float* w_in = (const float*)d_in[1];
  const float* b_in = (const float*)d_in[2];
  const float* ag   = (const float*)d_in[3];
  const float* ab   = (const float*)d_in[4];
  const float* Lre  = (const float*)d_in[5];
  const float* Lim  = (const float*)d_in[6];
  const float* Bre  = (const float*)d_in[7];
  const float* Bim  = (const float*)d_in[8];
  const float* Cre  = (const float*)d_in[9];
  const float* Cim  = (const float*)d_in[10];
  const float* Dv   = (const float*)d_in[11];
  const float* ls   = (const float*)d_in[12];
  const float* ffg  = (const float*)d_in[13];
  const float* ffb  = (const float*)d_in[14];
  const float* Wenc = (const float*)d_in[15];
  const float* Wdec = (const float*)d_in[16];
  const float* og   = (const float*)d_in[17];
  const float* ob   = (const float*)d_in[18];
  const float* Wout = (const float*)d_in[19];
  const float* bout = (const float*)d_in[20];
  float* ws  = (float*)d_ws;
  float* out = (float*)d_out;

  ssm_setup<<<1, 64, 0, stream>>>(w_in, b_in, ag, ab, Lre, Lim, Bre, Bim,
                                  Cre, Cim, Dv, ls, ffg, ffb, Wenc, Wdec,
                                  og, ob, Wout, bout, ws);
  ssm_main<<<NSEQ/64, 64, 0, stream>>>(x, ws, out);
}

// Round 4
// 118.395 us; speedup vs baseline: 1.1412x; 1.0339x over previous
//
#include <hip/hip_runtime.h>
#include <math.h>

// Problem constants: B=2, T=15, H=W=192, C=P=16
#define HW_TOT 36864      // 192*192
#define T_LEN  15
#define NSEQ   73728      // 2*36864
#define NBLK   576        // 2 sequences per thread, 64 threads/block

// staged ws layout (floats), ws[0..SM_N):
#define OFF_F1    4       // 0..3: Saa, 2*Sad, Sdd, pad
#define OFF_F2    20
#define OFF_F3    36
#define OFF_D     52
#define OFF_G3    68
#define OFF_G12   84      // [16][32]: row c, entries [2t]=G1[c,t], [2t+1]=G2[c,t]
#define OFF_WENC  596     // [32][16]
#define OFF_WDEC  1108    // [16][16]
#define OFF_WOUT  1364    // [16][16]
#define OFF_FFG   1620
#define OFF_FFB   1636
#define OFF_OG    1652
#define OFF_OB    1668
#define OFF_BOUT  1684
#define SM_N      1700

__device__ __forceinline__ float gelu_exact(float x){
  float ax = fabsf(x) * 0.7071067811865476f;
  float t  = 1.0f / (1.0f + 0.3275911f * ax);
  float poly = t*(0.254829592f + t*(-0.284496736f + t*(1.421413741f +
               t*(-1.453152027f + t*1.061405429f))));
  float er = 1.0f - poly * __expf(-ax*ax);
  er = copysignf(er, x);
  return 0.5f * x * (1.0f + er);
}

__global__ void __launch_bounds__(64) ssm_setup(
    const float* __restrict__ w_in, const float* __restrict__ b_in,
    const float* __restrict__ ag,   const float* __restrict__ ab,
    const float* __restrict__ Lre,  const float* __restrict__ Lim,
    const float* __restrict__ Bre,  const float* __restrict__ Bim,
    const float* __restrict__ Cre,  const float* __restrict__ Cim,
    const float* __restrict__ Dv,   const float* __restrict__ ls,
    const float* __restrict__ ffg,  const float* __restrict__ ffb,
    const float* __restrict__ Wenc, const float* __restrict__ Wdec,
    const float* __restrict__ og,   const float* __restrict__ ob,
    const float* __restrict__ Wout, const float* __restrict__ bout,
    float* __restrict__ ws)
{
  // U1[p][j] = Lam_bar^j * P1_p (complex), same for U2; Q = P3 * sum_j Lam_bar^j
  __shared__ float U1r[240], U1i[240], U2r[240], U2i[240];
  __shared__ float Cr[256], Ci[256], Qr[16], Qi[16];
  const int tid = threadIdx.x;

  float mw = 0.f, mb = 0.f;
  for (int c = 0; c < 16; ++c){ mw += w_in[c]; mb += b_in[c]; }
  mw *= 0.0625f; mb *= 0.0625f;
  float Saa = 0.f, Sad = 0.f, Sdd = 0.f;
  for (int c = 0; c < 16; ++c){
    float a = w_in[c]-mw, d = b_in[c]-mb;
    Saa += a*a; Sad += a*d; Sdd += d*d;
  }
  Saa *= 0.0625f; Sad *= 0.0625f; Sdd *= 0.0625f;
  if (tid == 0){ ws[0]=Saa; ws[1]=2.f*Sad; ws[2]=Sdd; ws[3]=0.f; }

  if (tid < 16){
    int c = tid;
    float a = w_in[c]-mw, d = b_in[c]-mb, g = ag[c];
    ws[OFF_F1+c] = a*g;
    ws[OFF_F2+c] = d*g;
    ws[OFF_F3+c] = ab[c];
    ws[OFF_D +c] = Dv[c];
    ws[OFF_FFG+c] = ffg[c];
    ws[OFF_FFB+c] = ffb[c];
    ws[OFF_OG +c] = og[c];
    ws[OFF_OB +c] = ob[c];
    ws[OFF_BOUT+c] = bout[c];
  }

  if (tid < 16){
    int p = tid;
    float step = expf(ls[p]);
    float lr = Lre[p], li = Lim[p];
    float er = expf(lr*step);
    float th = li*step;
    float Lbr = er*cosf(th), Lbi = er*sinf(th);   // Lam_bar
    float inv = 1.f/(lr*lr + li*li);
    float gr = Lbr - 1.f, gi = Lbi;
    float fr = (gr*lr + gi*li)*inv;
    float fi = (gi*lr - gr*li)*inv;
    float P1r=0,P1i=0,P2r=0,P2i=0,P3r=0,P3i=0;
    for (int c = 0; c < 16; ++c){
      float br = Bre[p*16+c], bi = Bim[p*16+c];
      float Bbr = fr*br - fi*bi, Bbi = fr*bi + fi*br;   // B_bar[p][c]
      float a = w_in[c]-mw, d = b_in[c]-mb, g = ag[c];
      float f1 = a*g, f2 = d*g, f3 = ab[c];
      P1r += f1*Bbr; P1i += f1*Bbi;
      P2r += f2*Bbr; P2i += f2*Bbi;
      P3r += f3*Bbr; P3i += f3*Bbi;
    }
    // powers: U1[p][j], U2[p][j], and K = sum Lam_bar^j
    float c1r=P1r, c1i=P1i, c2r=P2r, c2i=P2i;
    U1r[p*15+0]=c1r; U1i[p*15+0]=c1i;
    U2r[p*15+0]=c2r; U2i[p*15+0]=c2i;
    float kr=1.f, ki=0.f, pr=1.f, pi=0.f;
    for (int j = 1; j < T_LEN; ++j){
      float t1r = c1r*Lbr - c1i*Lbi, t1i = c1r*Lbi + c1i*Lbr;
      c1r=t1r; c1i=t1i;
      U1r[p*15+j]=c1r; U1i[p*15+j]=c1i;
      float t2r = c2r*Lbr - c2i*Lbi, t2i = c2r*Lbi + c2i*Lbr;
      c2r=t2r; c2i=t2i;
      U2r[p*15+j]=c2r; U2i[p*15+j]=c2i;
      float tpr = pr*Lbr - pi*Lbi, tpi = pr*Lbi + pi*Lbr;
      pr=tpr; pi=tpi;
      kr += pr; ki += pi;
    }
    Qr[p] = P3r*kr - P3i*ki;
    Qi[p] = P3r*ki + P3i*kr;
  }

  // masked Cm into shared
  for (int k = tid; k < 256; k += 64){
    int p = k & 15;
    float step = expf(ls[p]);
    float freq = step * fabsf(Lim[p]) * 0.15915494309189535f;
    float m = (freq < 0.25f) ? 1.f : 0.f;
    Cr[k] = Cre[k]*m;
    Ci[k] = Cim[k]*m;
  }
  for (int k = tid; k < 512; k += 64) ws[OFF_WENC+k] = Wenc[k];
  for (int k = tid; k < 256; k += 64) ws[OFF_WDEC+k] = Wdec[k];
  for (int k = tid; k < 256; k += 64) ws[OFF_WOUT+k] = Wout[k];

  __syncthreads();

  // G1[c,t] = Re(Cm[c,:] . U1[:,14-t]),  G2 likewise
  for (int idx = tid; idx < 240; idx += 64){
    int c = idx / 15, t = idx - 15*c, j = 14 - t;
    float g1 = 0.f, g2 = 0.f;
    for (int p = 0; p < 16; ++p){
      float cr = Cr[c*16+p], ci = Ci[c*16+p];
      g1 = fmaf(cr, U1r[p*15+j], fmaf(-ci, U1i[p*15+j], g1));
      g2 = fmaf(cr, U2r[p*15+j], fmaf(-ci, U2i[p*15+j], g2));
    }
    ws[OFF_G12 + c*32 + 2*t    ] = g1;
    ws[OFF_G12 + c*32 + 2*t + 1] = g2;
  }
  if (tid < 16){
    int c = tid;
    float g3 = 0.f;
    for (int p = 0; p < 16; ++p)
      g3 = fmaf(Cr[c*16+p], Qr[p], fmaf(-Ci[c*16+p], Qi[p], g3));
    ws[OFF_G3+c] = g3;
  }
}

__global__ void __launch_bounds__(64) ssm_main(
    const float* __restrict__ x, const float* __restrict__ ws,
    float* __restrict__ out)
{
  __shared__ float sm[SM_N];
  const int tid = threadIdx.x;

  // two sequences per thread: n0 and n0+64 (both coalesced across the wave)
  const int n0 = blockIdx.x * 128 + tid;
  const int n1 = n0 + 64;
  const int b0 = (n0 >= HW_TOT) ? 1 : 0;
  const int b1 = (n1 >= HW_TOT) ? 1 : 0;
  const int r0 = n0 - b0 * HW_TOT;
  const int r1 = n1 - b1 * HW_TOT;

  const float* xp0 = x + (size_t)b0 * (T_LEN * HW_TOT) + r0;
  const float* xp1 = x + (size_t)b1 * (T_LEN * HW_TOT) + r1;
  float xv[2][T_LEN];
#pragma unroll
  for (int t = 0; t < T_LEN; ++t){
    xv[0][t] = xp0[(size_t)t * HW_TOT];
    xv[1][t] = xp1[(size_t)t * HW_TOT];
  }

  for (int k = tid; k < SM_N; k += 64) sm[k] = ws[k];
  __syncthreads();

  const float Saa = sm[0], Sad2 = sm[1], Sdd = sm[2];
  float s1v[2][T_LEN], rsv[2][T_LEN];
#pragma unroll
  for (int s = 0; s < 2; ++s)
#pragma unroll
    for (int t = 0; t < T_LEN; ++t){
      float xt   = xv[s][t];
      float var  = fmaf(xt, fmaf(xt, Saa, Sad2), Sdd);
      float rstd = rsqrtf(var + 1e-5f);
      rsv[s][t] = rstd;
      s1v[s][t] = rstd * xt;
    }

  // y_c = G3_c + sum_t (s1_t*G1[c,t] + rstd_t*G2[c,t])   (both seqs share G reads)
  float z[2][16];
#pragma unroll
  for (int c = 0; c < 16; ++c){
    float a0 = sm[OFF_G3+c], a1 = a0;
#pragma unroll
    for (int t = 0; t < T_LEN; ++t){
      float g1 = sm[OFF_G12 + c*32 + 2*t];
      float g2 = sm[OFF_G12 + c*32 + 2*t + 1];
      a0 = fmaf(s1v[0][t], g1, fmaf(rsv[0][t], g2, a0));
      a1 = fmaf(s1v[1][t], g1, fmaf(rsv[1][t], g2, a1));
    }
    z[0][c] = a0; z[1][c] = a1;
  }

  // fx at t=T-1, then z = gelu(y + fx*D) + fx
  float fx[2][16];
#pragma unroll
  for (int s = 0; s < 2; ++s){
    const float s1L = s1v[s][T_LEN-1], rsL = rsv[s][T_LEN-1];
#pragma unroll
    for (int c = 0; c < 16; ++c){
      float f = fmaf(s1L, sm[OFF_F1+c], fmaf(rsL, sm[OFF_F2+c], sm[OFF_F3+c]));
      fx[s][c] = f;
      float y = fmaf(f, sm[OFF_D+c], z[s][c]);
      z[s][c] = gelu_exact(y) + f;
    }
  }

  // LN(z) -> fx2
  float fx2[2][16];
#pragma unroll
  for (int s = 0; s < 2; ++s){
    float mu = 0.f;
#pragma unroll
    for (int c = 0; c < 16; ++c) mu += z[s][c];
    mu *= 0.0625f;
    float vr = 0.f;
#pragma unroll
    for (int c = 0; c < 16; ++c){ float d = z[s][c]-mu; vr = fmaf(d,d,vr); }
    vr *= 0.0625f;
    float rs = rsqrtf(vr + 1e-5f);
#pragma unroll
    for (int c = 0; c < 16; ++c)
      fx2[s][c] = fmaf((z[s][c]-mu)*rs, sm[OFF_FFG+c], sm[OFF_FFB+c]);
  }

  // enc = fx2 @ Wenc^T ; h = a * gelu(g)   (weight reads shared between seqs)
  float hg[2][16];
#pragma unroll
  for (int c = 0; c < 16; ++c){
    float a0=0.f, g0=0.f, a1=0.f, g1=0.f;
#pragma unroll
    for (int k = 0; k < 16; ++k){
      float wa = sm[OFF_WENC + c*16 + k];
      float wg = sm[OFF_WENC + (16+c)*16 + k];
      a0 = fmaf(fx2[0][k], wa, a0); g0 = fmaf(fx2[0][k], wg, g0);
      a1 = fmaf(fx2[1][k], wa, a1); g1 = fmaf(fx2[1][k], wg, g1);
    }
    hg[0][c] = a0 * gelu_exact(g0);
    hg[1][c] = a1 * gelu_exact(g1);
  }

  // z2 = hg @ Wdec^T + fx2
  float z2[2][16];
#pragma unroll
  for (int c = 0; c < 16; ++c){
    float acc0 = fx2[0][c], acc1 = fx2[1][c];
#pragma unroll
    for (int k = 0; k < 16; ++k){
      float wd = sm[OFF_WDEC + c*16 + k];
      acc0 = fmaf(hg[0][k], wd, acc0);
      acc1 = fmaf(hg[1][k], wd, acc1);
    }
    z2[0][c] = acc0; z2[1][c] = acc1;
  }

  // final LN -> qv
  float qv[2][16];
#pragma unroll
  for (int s = 0; s < 2; ++s){
    float mu = 0.f;
#pragma unroll
    for (int c = 0; c < 16; ++c) mu += z2[s][c];
    mu *= 0.0625f;
    float vr = 0.f;
#pragma unroll
    for (int c = 0; c < 16; ++c){ float d = z2[s][c]-mu; vr = fmaf(d,d,vr); }
    vr *= 0.0625f;
    float rs = rsqrtf(vr + 1e-5f);
#pragma unroll
    for (int c = 0; c < 16; ++c)
      qv[s][c] = fmaf((z2[s][c]-mu)*rs, sm[OFF_OG+c], sm[OFF_OB+c]);
  }

  // out head + store (16 coalesced planes per seq)
  float* op0 = out + (size_t)b0 * (16*HW_TOT) + r0;
  float* op1 = out + (size_t)b1 * (16*HW_TOT) + r1;
#pragma unroll
  for (int c = 0; c < 16; ++c){
    float acc0 = sm[OFF_BOUT+c], acc1 = acc0;
#pragma unroll
    for (int k = 0; k < 16; ++k){
      float wo = sm[OFF_WOUT + c*16 + k];
      acc0 = fmaf(qv[0][k], wo, acc0);
      acc1 = fmaf(qv[1][k], wo, acc1);
    }
    op0[(size_t)c * HW_TOT] = acc0;
    op1[(size_t)c * HW_TOT] = acc1;
  }
}

extern "C" void kernel_launch(void* const* d_in, const int* in_sizes, int n_in,
                              void* d_out, int out_size, void* d_ws, size_t ws_size,
                              hipStream_t stream)
{
  const float* x    = (const float*)d_in[0];
  const float* w_in = (const float*)d_in[1];
  const float* b_in = (const float*)d_in[2];
  const float* ag   = (const float*)d_in[3];
  const float* ab   = (const float*)d_in[4];
  const float* Lre  = (const float*)d_in[5];
  const float* Lim  = (const float*)d_in[6];
  const float* Bre  = (const float*)d_in[7];
  const float* Bim  = (const float*)d_in[8];
  const float* Cre  = (const float*)d_in[9];
  const float* Cim  = (const float*)d_in[10];
  const float* Dv   = (const float*)d_in[11];
  const float* ls   = (const float*)d_in[12];
  const float* ffg  = (const float*)d_in[13];
  const float* ffb  = (const float*)d_in[14];
  const float* Wenc = (const float*)d_in[15];
  const float* Wdec = (const float*)d_in[16];
  const float* og   = (const float*)d_in[17];
  const float* ob   = (const float*)d_in[18];
  const float* Wout = (const float*)d_in[19];
  const float* bout = (const float*)d_in[20];
  float* ws  = (float*)d_ws;
  float* out = (float*)d_out;

  ssm_setup<<<1, 64, 0, stream>>>(w_in, b_in, ag, ab, Lre, Lim, Bre, Bim,
                                  Cre, Cim, Dv, ls, ffg, ffb, Wenc, Wdec,
                                  og, ob, Wout, bout, ws);
  ssm_main<<<NBLK, 64, 0, stream>>>(x, ws, out);
}